// Round 1
// baseline (70.111 us; speedup 1.0000x reference)
//
#include <hip/hip_runtime.h>
#include <hip/hip_bf16.h>

// GraspHD encoder:
//   counts[t,p,n] = sum of 8x8 block of x            (T=100, P=2, NB=300)
//   bundled[d]    = sum_{t,p,n} sin(counts*w[d]) * pos[n,d]*pol[p,d]*time[t,d]
//   out[d]        = sign(bundled[d])                 (D=4096)
// pos/pol/time are exactly +-1.0f -> fold into sign-bit XOR.
// sin via hardware v_fract + v_sin (input in revolutions), w pre-scaled by 1/2pi.

#define T_ 100
#define P_ 2
#define H_ 120
#define W_ 160
#define BS_ 8
#define HB_ 15
#define WB_ 20
#define NB_ 300
#define D_ 4096
#define TC_ 2            // t-values per chunk
#define G_ (T_ / TC_)    // 50 chunks

// ---------------- kernel 1: per-block event counts ----------------
__global__ __launch_bounds__(256) void k_counts(const float* __restrict__ x,
                                                float* __restrict__ counts) {
    int idx = blockIdx.x * 256 + threadIdx.x;           // (t*P + p)*NB + n
    if (idx >= T_ * P_ * NB_) return;
    int n  = idx % NB_;
    int tp = idx / NB_;
    int hb = n / WB_;
    int wb = n % WB_;
    const float* base = x + ((size_t)tp * H_ + hb * BS_) * W_ + wb * BS_;
    float s = 0.f;
#pragma unroll
    for (int i = 0; i < BS_; ++i) {
        const float4* row = reinterpret_cast<const float4*>(base + i * W_);
        float4 a = row[0];
        float4 b = row[1];
        s += a.x + a.y + a.z + a.w + b.x + b.y + b.z + b.w;
    }
    counts[idx] = s;
}

// ---------------- kernel 2: main bind+bundle partial sums ----------------
// grid: (D/256, G);  block 256.  Each thread owns one d, iterates its t-chunk.
__global__ __launch_bounds__(256) void k_encode(const float* __restrict__ counts,
                                                const float* __restrict__ proj_w,
                                                const float* __restrict__ pos_hv,
                                                const float* __restrict__ pol_hv,
                                                const float* __restrict__ time_hv,
                                                float* __restrict__ partial) {
    // LDS: counts for this t-chunk, layout cq[n] = {c[t0,p0], c[t0,p1], c[t1,p0], c[t1,p1]}
    __shared__ float4 cq[NB_];

    const int d  = blockIdx.x * 256 + threadIdx.x;
    const int t0 = blockIdx.y * TC_;

    for (int e = threadIdx.x; e < NB_ * 4; e += 256) {
        int n  = e >> 2;
        int tl = (e >> 1) & 1;
        int p  = e & 1;
        reinterpret_cast<float*>(cq)[e] = counts[((t0 + tl) * P_ + p) * NB_ + n];
    }

    const float wp = proj_w[d] * 0.15915494309189535f;   // 1/(2*pi)

    const unsigned SGN = 0x80000000u;
    unsigned tp0 = __float_as_uint(time_hv[(size_t)t0 * D_ + d]);
    unsigned tp1 = __float_as_uint(time_hv[(size_t)(t0 + 1) * D_ + d]);
    unsigned pl0 = __float_as_uint(pol_hv[d]);
    unsigned pl1 = __float_as_uint(pol_hv[D_ + d]);
    const unsigned m00 = (tp0 ^ pl0) & SGN;
    const unsigned m01 = (tp0 ^ pl1) & SGN;
    const unsigned m10 = (tp1 ^ pl0) & SGN;
    const unsigned m11 = (tp1 ^ pl1) & SGN;

    __syncthreads();

    float acc = 0.f;
#pragma unroll 4
    for (int n = 0; n < NB_; ++n) {
        float4 c = cq[n];
        unsigned mn = __float_as_uint(pos_hv[(size_t)n * D_ + d]) & SGN;

        float s0 = __builtin_amdgcn_sinf(__builtin_amdgcn_fractf(c.x * wp));
        float s1 = __builtin_amdgcn_sinf(__builtin_amdgcn_fractf(c.y * wp));
        float s2 = __builtin_amdgcn_sinf(__builtin_amdgcn_fractf(c.z * wp));
        float s3 = __builtin_amdgcn_sinf(__builtin_amdgcn_fractf(c.w * wp));

        acc += __uint_as_float(__float_as_uint(s0) ^ (mn ^ m00));
        acc += __uint_as_float(__float_as_uint(s1) ^ (mn ^ m01));
        acc += __uint_as_float(__float_as_uint(s2) ^ (mn ^ m10));
        acc += __uint_as_float(__float_as_uint(s3) ^ (mn ^ m11));
    }

    partial[(size_t)blockIdx.y * D_ + d] = acc;
}

// ---------------- kernel 3: deterministic reduce + sign ----------------
__global__ __launch_bounds__(256) void k_reduce(const float* __restrict__ partial,
                                                float* __restrict__ out) {
    int d = blockIdx.x * 256 + threadIdx.x;
    float a = 0.f;
    for (int g = 0; g < G_; ++g) a += partial[(size_t)g * D_ + d];
    out[d] = (a > 0.f) ? 1.f : ((a < 0.f) ? -1.f : 0.f);
}

extern "C" void kernel_launch(void* const* d_in, const int* in_sizes, int n_in,
                              void* d_out, int out_size, void* d_ws, size_t ws_size,
                              hipStream_t stream) {
    const float* x       = (const float*)d_in[0];
    const float* proj_w  = (const float*)d_in[1];
    const float* pos_hv  = (const float*)d_in[2];
    const float* pol_hv  = (const float*)d_in[3];
    const float* time_hv = (const float*)d_in[4];
    float* out = (float*)d_out;

    // workspace layout: counts (60000 f32) at 0, partials (G*D f32) at 256 KiB
    float* counts  = (float*)d_ws;
    float* partial = (float*)((char*)d_ws + (256u << 10));

    {
        int total = T_ * P_ * NB_;
        k_counts<<<dim3((total + 255) / 256), dim3(256), 0, stream>>>(x, counts);
    }
    {
        dim3 grid(D_ / 256, G_);
        k_encode<<<grid, dim3(256), 0, stream>>>(counts, proj_w, pos_hv, pol_hv,
                                                 time_hv, partial);
    }
    k_reduce<<<dim3(D_ / 256), dim3(256), 0, stream>>>(partial, out);
}

// Round 2
// 59.841 us; speedup vs baseline: 1.1716x; 1.1716x over previous
//
#include <hip/hip_runtime.h>
#include <hip/hip_bf16.h>

// GraspHD encoder:
//   counts[t,p,n] = sum of 8x8 block of x            (T=100, P=2, NB=300)
//   bundled[d]    = sum_{t,p,n} sin(counts*w[d]) * pos[n,d]*pol[p,d]*time[t,d]
//   out[d]        = sign(bundled[d])                 (D=4096)
// pos/pol/time are exactly +-1.0f. Fold the sign product INTO the sin
// argument's sign bit (sin(s*x) = s*sin(x) for s=+-1): per-n cost is
// 1 and + 4 xor + 4 mul + 4 fract + 4 sin + 4 add for 4 sin terms.
// sin via hardware v_fract + v_sin (input in revolutions), w pre-scaled 1/2pi.

#define T_ 100
#define P_ 2
#define H_ 120
#define W_ 160
#define BS_ 8
#define HB_ 15
#define WB_ 20
#define NB_ 300
#define NH_ 150          // n-half length
#define D_ 4096
#define TC_ 2            // t-values per chunk
#define G_ 100           // chunks = (T/TC) * 2 n-halves

// ---------------- kernel 1: per-block event counts ----------------
__global__ __launch_bounds__(256) void k_counts(const float* __restrict__ x,
                                                float* __restrict__ counts) {
    int idx = blockIdx.x * 256 + threadIdx.x;           // (t*P + p)*NB + n
    if (idx >= T_ * P_ * NB_) return;
    int n  = idx % NB_;
    int tp = idx / NB_;
    int hb = n / WB_;
    int wb = n % WB_;
    const float* base = x + ((size_t)tp * H_ + hb * BS_) * W_ + wb * BS_;
    float s = 0.f;
#pragma unroll
    for (int i = 0; i < BS_; ++i) {
        const float4* row = reinterpret_cast<const float4*>(base + i * W_);
        float4 a = row[0];
        float4 b = row[1];
        s += a.x + a.y + a.z + a.w + b.x + b.y + b.z + b.w;
    }
    counts[idx] = s;
}

// ---------------- kernel 2: main bind+bundle partial sums ----------------
// grid: (D/256, G).  blockIdx.y -> (t-pair, n-half). Each thread owns one d.
__global__ __launch_bounds__(256) void k_encode(const float* __restrict__ counts,
                                                const float* __restrict__ proj_w,
                                                const float* __restrict__ pos_hv,
                                                const float* __restrict__ pol_hv,
                                                const float* __restrict__ time_hv,
                                                float* __restrict__ partial) {
    // LDS: counts for this (t-pair, n-half):
    // cq[n] = {c[t0,p0], c[t0,p1], c[t1,p0], c[t1,p1]}
    __shared__ float4 cq[NH_];

    const int d  = blockIdx.x * 256 + threadIdx.x;
    const int tc = blockIdx.y >> 1;
    const int nh = blockIdx.y & 1;
    const int t0 = tc * TC_;
    const int n0 = nh * NH_;

    for (int e = threadIdx.x; e < NH_ * 4; e += 256) {
        int n  = e >> 2;
        int tl = (e >> 1) & 1;
        int p  = e & 1;
        reinterpret_cast<float*>(cq)[e] = counts[((t0 + tl) * P_ + p) * NB_ + n0 + n];
    }

    const float wp = proj_w[d] * 0.15915494309189535f;   // 1/(2*pi)

    const unsigned SGN = 0x80000000u;
    const unsigned uw  = __float_as_uint(wp);
    unsigned tp0 = __float_as_uint(time_hv[(size_t)t0 * D_ + d]) & SGN;
    unsigned tp1 = __float_as_uint(time_hv[(size_t)(t0 + 1) * D_ + d]) & SGN;
    unsigned pl0 = __float_as_uint(pol_hv[d]) & SGN;
    unsigned pl1 = __float_as_uint(pol_hv[D_ + d]) & SGN;
    const unsigned u00 = uw ^ (tp0 ^ pl0);
    const unsigned u01 = uw ^ (tp0 ^ pl1);
    const unsigned u10 = uw ^ (tp1 ^ pl0);
    const unsigned u11 = uw ^ (tp1 ^ pl1);

    __syncthreads();

    const float* pp = pos_hv + (size_t)n0 * D_ + d;
    float a0 = 0.f, a1 = 0.f, a2 = 0.f, a3 = 0.f;
#pragma unroll 2
    for (int n = 0; n < NH_; ++n) {
        float4 c = cq[n];
        unsigned mn = __float_as_uint(*pp) & SGN;
        pp += D_;
        float w0 = __uint_as_float(u00 ^ mn);
        float w1 = __uint_as_float(u01 ^ mn);
        float w2 = __uint_as_float(u10 ^ mn);
        float w3 = __uint_as_float(u11 ^ mn);
        a0 += __builtin_amdgcn_sinf(__builtin_amdgcn_fractf(c.x * w0));
        a1 += __builtin_amdgcn_sinf(__builtin_amdgcn_fractf(c.y * w1));
        a2 += __builtin_amdgcn_sinf(__builtin_amdgcn_fractf(c.z * w2));
        a3 += __builtin_amdgcn_sinf(__builtin_amdgcn_fractf(c.w * w3));
    }

    partial[(size_t)blockIdx.y * D_ + d] = (a0 + a1) + (a2 + a3);
}

// ---------------- kernel 3: deterministic reduce + sign ----------------
__global__ __launch_bounds__(256) void k_reduce(const float* __restrict__ partial,
                                                float* __restrict__ out) {
    int d = blockIdx.x * 256 + threadIdx.x;
    float a = 0.f;
    for (int g = 0; g < G_; ++g) a += partial[(size_t)g * D_ + d];
    out[d] = (a > 0.f) ? 1.f : ((a < 0.f) ? -1.f : 0.f);
}

extern "C" void kernel_launch(void* const* d_in, const int* in_sizes, int n_in,
                              void* d_out, int out_size, void* d_ws, size_t ws_size,
                              hipStream_t stream) {
    const float* x       = (const float*)d_in[0];
    const float* proj_w  = (const float*)d_in[1];
    const float* pos_hv  = (const float*)d_in[2];
    const float* pol_hv  = (const float*)d_in[3];
    const float* time_hv = (const float*)d_in[4];
    float* out = (float*)d_out;

    // workspace layout: counts (60000 f32) at 0, partials (G*D f32) at 256 KiB
    float* counts  = (float*)d_ws;
    float* partial = (float*)((char*)d_ws + (256u << 10));

    {
        int total = T_ * P_ * NB_;
        k_counts<<<dim3((total + 255) / 256), dim3(256), 0, stream>>>(x, counts);
    }
    {
        dim3 grid(D_ / 256, G_);
        k_encode<<<grid, dim3(256), 0, stream>>>(counts, proj_w, pos_hv, pol_hv,
                                                 time_hv, partial);
    }
    k_reduce<<<dim3(D_ / 256), dim3(256), 0, stream>>>(partial, out);
}